// Round 1
// baseline (1421.908 us; speedup 1.0000x reference)
//
#include <hip/hip_runtime.h>
#include <hip/hip_bf16.h>

// Shapes (from reference setup): B=128, N=50, NB=32, K=8, H=64, D=K*H=512.
// sites = B*N = 6400; neighbor rows = B*N*NB = 204800.
// Phase 1: z = l2norm_groups64(relu(X @ W1^T + b1)) for self (6400 rows) and
//          neighbors (204800 rows), written to workspace.
// Phase 2: routing iterations per site with nz [32][512] staged in LDS.

#define D_DIM 512
#define BM 128
#define BN 128
#define BK 16

// 256 threads = 16x16; each thread computes an 8x8 sub-tile.
// As/Ws stored transposed [k][row] so fragments are ds_read_b128.
__global__ __launch_bounds__(256) void gemm_proj_norm(
    const float* __restrict__ A,    // [R, 512] row-major
    const float* __restrict__ W,    // [512, 512] row-major (we compute A @ W^T)
    const float* __restrict__ bias, // [512]
    float* __restrict__ Z)          // [R, 512] normalized output
{
    __shared__ float As[BK][BM];  // 8 KB
    __shared__ float Ws[BK][BN];  // 8 KB

    const int tid = threadIdx.x;
    const int ty = tid >> 4;      // 0..15 (row group)
    const int tx = tid & 15;      // 0..15 (col group)
    const size_t row0 = (size_t)blockIdx.x * BM;
    const int col0 = blockIdx.y * BN;

    float acc[8][8] = {};

    for (int k0 = 0; k0 < D_DIM; k0 += BK) {
        // Stage tiles: 128 rows x 16 k each = 512 float4 per operand; 2 per thread.
        #pragma unroll
        for (int j = 0; j < 2; ++j) {
            const int idx = tid * 2 + j;   // 0..511
            const int r = idx >> 2;        // 0..127
            const int kq = idx & 3;        // which float4 of the 16-k row chunk
            const float4 av = *reinterpret_cast<const float4*>(
                &A[(row0 + r) * D_DIM + k0 + kq * 4]);
            As[kq * 4 + 0][r] = av.x;
            As[kq * 4 + 1][r] = av.y;
            As[kq * 4 + 2][r] = av.z;
            As[kq * 4 + 3][r] = av.w;
            const float4 wv = *reinterpret_cast<const float4*>(
                &W[(size_t)(col0 + r) * D_DIM + k0 + kq * 4]);
            Ws[kq * 4 + 0][r] = wv.x;
            Ws[kq * 4 + 1][r] = wv.y;
            Ws[kq * 4 + 2][r] = wv.z;
            Ws[kq * 4 + 3][r] = wv.w;
        }
        __syncthreads();

        #pragma unroll
        for (int kk = 0; kk < BK; ++kk) {
            float a[8], w[8];
            *reinterpret_cast<float4*>(&a[0]) = *reinterpret_cast<float4*>(&As[kk][ty * 8]);
            *reinterpret_cast<float4*>(&a[4]) = *reinterpret_cast<float4*>(&As[kk][ty * 8 + 4]);
            *reinterpret_cast<float4*>(&w[0]) = *reinterpret_cast<float4*>(&Ws[kk][tx * 8]);
            *reinterpret_cast<float4*>(&w[4]) = *reinterpret_cast<float4*>(&Ws[kk][tx * 8 + 4]);
            #pragma unroll
            for (int i = 0; i < 8; ++i)
                #pragma unroll
                for (int j = 0; j < 8; ++j)
                    acc[i][j] = fmaf(a[i], w[j], acc[i][j]);
        }
        __syncthreads();
    }

    // Epilogue: +bias, ReLU, l2norm over each 64-col capsule group, store.
    // col0 % 64 == 0, so the tx octet (tx 0..7 / 8..15) spans exactly one group.
    float bcol[8];
    #pragma unroll
    for (int j = 0; j < 8; ++j) bcol[j] = bias[col0 + tx * 8 + j];

    #pragma unroll
    for (int i = 0; i < 8; ++i) {
        float ss = 0.0f;
        #pragma unroll
        for (int j = 0; j < 8; ++j) {
            float v = fmaxf(acc[i][j] + bcol[j], 0.0f);
            acc[i][j] = v;
            ss = fmaf(v, v, ss);
        }
        // reduce across the 8 lanes sharing (row, group): lanes differ in tx bits 0..2
        ss += __shfl_xor(ss, 1);
        ss += __shfl_xor(ss, 2);
        ss += __shfl_xor(ss, 4);
        const float inv = 1.0f / fmaxf(sqrtf(ss), 1e-12f);
        const size_t r = row0 + ty * 8 + i;
        float4 o0, o1;
        o0.x = acc[i][0] * inv; o0.y = acc[i][1] * inv;
        o0.z = acc[i][2] * inv; o0.w = acc[i][3] * inv;
        o1.x = acc[i][4] * inv; o1.y = acc[i][5] * inv;
        o1.z = acc[i][6] * inv; o1.w = acc[i][7] * inv;
        *reinterpret_cast<float4*>(&Z[r * D_DIM + col0 + tx * 8]) = o0;
        *reinterpret_cast<float4*>(&Z[r * D_DIM + col0 + tx * 8 + 4]) = o1;
    }
}

// One block per (b,n) site. nz [32][512] staged in LDS (64 KB).
// Each thread owns 2 of the 512 u-elements: e0 = t (k in 0..3), e1 = t+256 (k in 4..7).
// Wave w holds exactly group k=w (via e0) and k=w+4 (via e1) -> wave-wide l2norm.
__global__ __launch_bounds__(256) void routing_iters(
    const float* __restrict__ NZ,   // [sites, 32, 512] normalized
    const float* __restrict__ S,    // [sites, 512] normalized
    const int* __restrict__ miter_ptr,
    float* __restrict__ out)        // [sites, 512]
{
    __shared__ float nz[32 * 512];  // 64 KB
    __shared__ float u[512];
    __shared__ float p[256];

    const int site = blockIdx.x;
    const int t = threadIdx.x;
    const int lane = t & 63;

    // Load nz: 16384 floats = 4096 float4, 16 per thread, coalesced.
    const float4* src = reinterpret_cast<const float4*>(NZ + (size_t)site * 32 * D_DIM);
    float4* dst = reinterpret_cast<float4*>(nz);
    #pragma unroll
    for (int i = 0; i < 16; ++i) dst[t + 256 * i] = src[t + 256 * i];

    const int e0 = t, e1 = t + 256;
    const float s0 = S[(size_t)site * D_DIM + e0];
    const float s1 = S[(size_t)site * D_DIM + e1];
    const int miter = *miter_ptr;

    __syncthreads();

    // Iteration 0: p uniform = 1/8.
    float a0 = 0.0f, a1 = 0.0f;
    for (int m = 0; m < 32; ++m) {
        a0 += nz[m * D_DIM + e0];
        a1 += nz[m * D_DIM + e1];
    }
    float v0 = fmaf(a0, 0.125f, s0);
    float v1 = fmaf(a1, 0.125f, s1);

    const int m_ = t >> 3;          // 0..31 (neighbor for this thread's p-dot)
    const int k_ = t & 7;           // 0..7  (capsule for this thread's p-dot)
    const int k0 = e0 >> 6;         // 0..3
    const int k1 = e1 >> 6;         // 4..7

    for (int it = 1; it < miter; ++it) {
        // Normalize previous u per capsule group (full-wave reduce) and publish.
        float ss0 = v0 * v0, ss1 = v1 * v1;
        #pragma unroll
        for (int off = 32; off >= 1; off >>= 1) {
            ss0 += __shfl_xor(ss0, off);
            ss1 += __shfl_xor(ss1, off);
        }
        v0 *= 1.0f / fmaxf(sqrtf(ss0), 1e-12f);
        v1 *= 1.0f / fmaxf(sqrtf(ss1), 1e-12f);
        u[e0] = v0;
        u[e1] = v1;
        __syncthreads();

        // p[m_][k_] = dot(nz[m_, k_*64 : +64], u[k_*64 : +64]); lane-staggered (2-way LDS, free)
        float dot = 0.0f;
        const int base = m_ * D_DIM + k_ * 64;
        const int ub = k_ * 64;
        #pragma unroll
        for (int i = 0; i < 64; ++i) {
            const int hh = (i + lane) & 63;
            dot = fmaf(nz[base + hh], u[ub + hh], dot);
        }
        // softmax over k (8 consecutive lanes share m_)
        float mx = dot;
        mx = fmaxf(mx, __shfl_xor(mx, 1));
        mx = fmaxf(mx, __shfl_xor(mx, 2));
        mx = fmaxf(mx, __shfl_xor(mx, 4));
        const float pe = __expf(dot - mx);
        float psum = pe;
        psum += __shfl_xor(psum, 1);
        psum += __shfl_xor(psum, 2);
        psum += __shfl_xor(psum, 4);
        p[t] = pe / psum;   // p[m_*8 + k_]
        __syncthreads();

        // u = s + sum_m nz[m]*p[m,k]
        a0 = 0.0f; a1 = 0.0f;
        for (int m = 0; m < 32; ++m) {
            a0 = fmaf(nz[m * D_DIM + e0], p[m * 8 + k0], a0);
            a1 = fmaf(nz[m * D_DIM + e1], p[m * 8 + k1], a1);
        }
        v0 = s0 + a0;
        v1 = s1 + a1;
        __syncthreads();
    }

    out[(size_t)site * D_DIM + e0] = fmaxf(v0, 0.0f);
    out[(size_t)site * D_DIM + e1] = fmaxf(v1, 0.0f);
}

extern "C" void kernel_launch(void* const* d_in, const int* in_sizes, int n_in,
                              void* d_out, int out_size, void* d_ws, size_t ws_size,
                              hipStream_t stream) {
    const float* self_v  = (const float*)d_in[0];   // [B,N,512]
    const float* neigh_v = (const float*)d_in[1];   // [B,N,32,512]
    const float* W1      = (const float*)d_in[2];   // [512,512]
    const float* b1      = (const float*)d_in[3];   // [512]
    const int*   miter   = (const int*)d_in[4];     // scalar
    float* out = (float*)d_out;

    const int sites = in_sizes[0] / D_DIM;          // 6400
    const int nrows = in_sizes[1] / D_DIM;          // 204800

    float* nz = (float*)d_ws;                       // [nrows, 512]
    float* s  = nz + (size_t)nrows * D_DIM;         // [sites, 512]

    dim3 blk(256);
    // Neighbor projection + norm (the big GEMM): grid 1600 x 4
    gemm_proj_norm<<<dim3(nrows / BM, D_DIM / BN), blk, 0, stream>>>(neigh_v, W1, b1, nz);
    // Self projection + norm: grid 50 x 4
    gemm_proj_norm<<<dim3(sites / BM, D_DIM / BN), blk, 0, stream>>>(self_v, W1, b1, s);
    // Routing iterations
    routing_iters<<<dim3(sites), blk, 0, stream>>>(nz, s, miter, out);
}

// Round 2
// 521.774 us; speedup vs baseline: 2.7251x; 2.7251x over previous
//
#include <hip/hip_runtime.h>
#include <hip/hip_bf16.h>

// B=128, N=50, NB=32, K=8, H=64, D=512. sites=6400, neighbor rows=204800.
// Phase 0: W1 fp32 -> bf16 (once per call, into ws).
// Phase 1: Z = l2norm_g64(relu(X @ W^T + b)) via bf16 MFMA, fp32 accum; Z bf16.
// Phase 2: routing iterations per site, nz [32][512] in LDS as fp32.

#define D_DIM 512

typedef __attribute__((ext_vector_type(8))) short short8;
typedef __attribute__((ext_vector_type(4))) float f32x4;

__device__ __forceinline__ short f2bf(float f) {
    __bf16 b = (__bf16)f;
    return __builtin_bit_cast(short, b);
}
__device__ __forceinline__ float bf2f(short s) {
    unsigned u = ((unsigned)(unsigned short)s) << 16;
    return __builtin_bit_cast(float, u);
}

__global__ __launch_bounds__(256) void wconv(const float* __restrict__ W,
                                             short* __restrict__ Wb) {
    const int i = (blockIdx.x * 256 + threadIdx.x) * 8;
    const float4 v0 = *reinterpret_cast<const float4*>(W + i);
    const float4 v1 = *reinterpret_cast<const float4*>(W + i + 4);
    short8 o;
    o[0] = f2bf(v0.x); o[1] = f2bf(v0.y); o[2] = f2bf(v0.z); o[3] = f2bf(v0.w);
    o[4] = f2bf(v1.x); o[5] = f2bf(v1.y); o[6] = f2bf(v1.z); o[7] = f2bf(v1.w);
    *reinterpret_cast<short8*>(Wb + i) = o;
}

// 128x128 tile, BK=64. 256 threads = 4 waves (2x2), each wave 64x64 (4x4 MFMA frags).
// LDS tiles [128 rows][64 bf16] with XOR slot swizzle: slot' = slot ^ (row&7).
__global__ __launch_bounds__(256, 2) void gemm_mfma(
    const float* __restrict__ A,    // [R,512] fp32
    const short* __restrict__ Wb,   // [512,512] bf16 bits
    const float* __restrict__ bias, // [512]
    short* __restrict__ Z)          // [R,512] bf16 bits, l2-normalized groups
{
    __shared__ short lA[128 * 64];  // 16 KB
    __shared__ short lB[128 * 64];  // 16 KB

    const int t = threadIdx.x;
    const int lane = t & 63;
    const int wid = t >> 6;
    const size_t row0 = (size_t)blockIdx.x * 128;
    const int col0 = blockIdx.y * 128;
    const int wr = (wid >> 1) * 64;
    const int wc = (wid & 1) * 64;

    const int srow = t >> 3;   // 0..31 (staging row within 32-row stripe)
    const int sg = t & 7;      // 0..7  (8-elem slot)

    float4 ra[8];   // A staging regs: 4 chunks x 2 float4
    short8 rb[4];   // B staging regs

    auto loadA = [&](int k0) {
        #pragma unroll
        for (int j = 0; j < 4; ++j) {
            const float* p = A + (row0 + j * 32 + srow) * D_DIM + k0 + sg * 8;
            ra[j * 2]     = *reinterpret_cast<const float4*>(p);
            ra[j * 2 + 1] = *reinterpret_cast<const float4*>(p + 4);
        }
    };
    auto loadB = [&](int k0) {
        #pragma unroll
        for (int j = 0; j < 4; ++j) {
            rb[j] = *reinterpret_cast<const short8*>(
                Wb + (size_t)(col0 + j * 32 + srow) * D_DIM + k0 + sg * 8);
        }
    };
    auto writeLDS = [&]() {
        #pragma unroll
        for (int j = 0; j < 4; ++j) {
            const int row = j * 32 + srow;
            const int off = row * 64 + ((sg ^ (row & 7)) * 8);
            short8 c;
            c[0] = f2bf(ra[j*2].x);   c[1] = f2bf(ra[j*2].y);
            c[2] = f2bf(ra[j*2].z);   c[3] = f2bf(ra[j*2].w);
            c[4] = f2bf(ra[j*2+1].x); c[5] = f2bf(ra[j*2+1].y);
            c[6] = f2bf(ra[j*2+1].z); c[7] = f2bf(ra[j*2+1].w);
            *reinterpret_cast<short8*>(lA + off) = c;
            *reinterpret_cast<short8*>(lB + off) = rb[j];
        }
    };

    f32x4 acc[4][4] = {};

    auto compute = [&]() {
        #pragma unroll
        for (int kh = 0; kh < 2; ++kh) {
            short8 af[4], bfr[4];
            const int slot = kh * 4 + (lane >> 4);
            #pragma unroll
            for (int m = 0; m < 4; ++m) {
                const int arow = wr + m * 16 + (lane & 15);
                af[m] = *reinterpret_cast<const short8*>(
                    lA + arow * 64 + ((slot ^ (arow & 7)) * 8));
            }
            #pragma unroll
            for (int n = 0; n < 4; ++n) {
                const int brow = wc + n * 16 + (lane & 15);
                bfr[n] = *reinterpret_cast<const short8*>(
                    lB + brow * 64 + ((slot ^ (brow & 7)) * 8));
            }
            #pragma unroll
            for (int m = 0; m < 4; ++m)
                #pragma unroll
                for (int n = 0; n < 4; ++n)
                    acc[m][n] = __builtin_amdgcn_mfma_f32_16x16x32_bf16(
                        af[m], bfr[n], acc[m][n], 0, 0, 0);
        }
    };

    loadA(0); loadB(0);
    writeLDS();
    __syncthreads();
    for (int tk = 0; tk < 8; ++tk) {
        if (tk < 7) { loadA((tk + 1) * 64); loadB((tk + 1) * 64); }  // issue early
        compute();
        __syncthreads();
        if (tk < 7) { writeLDS(); __syncthreads(); }
    }

    // Epilogue: bias + ReLU + l2norm over the wave's 64-col capsule group.
    const int cbase = col0 + wc + (lane & 15);
    const int g = lane >> 4;
    float bcol[4];
    #pragma unroll
    for (int n = 0; n < 4; ++n) bcol[n] = bias[cbase + n * 16];

    #pragma unroll
    for (int m = 0; m < 4; ++m) {
        #pragma unroll
        for (int r = 0; r < 4; ++r) {
            float v[4];
            float ss = 0.0f;
            #pragma unroll
            for (int n = 0; n < 4; ++n) {
                v[n] = fmaxf(acc[m][n][r] + bcol[n], 0.0f);
                ss = fmaf(v[n], v[n], ss);
            }
            ss += __shfl_xor(ss, 1);
            ss += __shfl_xor(ss, 2);
            ss += __shfl_xor(ss, 4);
            ss += __shfl_xor(ss, 8);
            const float inv = 1.0f / fmaxf(sqrtf(ss), 1e-12f);
            const size_t orow = row0 + wr + m * 16 + g * 4 + r;
            #pragma unroll
            for (int n = 0; n < 4; ++n)
                Z[orow * D_DIM + cbase + n * 16] = f2bf(v[n] * inv);
        }
    }
}

// One block per (b,n) site. nz [32][512] fp32 in LDS (64 KB), sourced from bf16.
__global__ __launch_bounds__(256) void routing_iters(
    const short* __restrict__ NZ,   // [sites,32,512] bf16 normalized
    const short* __restrict__ S,    // [sites,512] bf16 normalized
    const int* __restrict__ miter_ptr,
    float* __restrict__ out)        // [sites,512]
{
    __shared__ float nz[32 * 512];
    __shared__ float u[512];
    __shared__ float p[256];

    const int site = blockIdx.x;
    const int t = threadIdx.x;
    const int lane = t & 63;

    const short8* src = reinterpret_cast<const short8*>(NZ + (size_t)site * 32 * D_DIM);
    #pragma unroll
    for (int i = 0; i < 8; ++i) {
        const short8 c = src[t + 256 * i];
        const int base = (t + 256 * i) * 8;
        float4 f0, f1;
        f0.x = bf2f(c[0]); f0.y = bf2f(c[1]); f0.z = bf2f(c[2]); f0.w = bf2f(c[3]);
        f1.x = bf2f(c[4]); f1.y = bf2f(c[5]); f1.z = bf2f(c[6]); f1.w = bf2f(c[7]);
        *reinterpret_cast<float4*>(nz + base) = f0;
        *reinterpret_cast<float4*>(nz + base + 4) = f1;
    }

    const int e0 = t, e1 = t + 256;
    const float s0 = bf2f(S[(size_t)site * D_DIM + e0]);
    const float s1 = bf2f(S[(size_t)site * D_DIM + e1]);
    const int miter = *miter_ptr;

    __syncthreads();

    // Iteration 0: p uniform = 1/8.
    float a0 = 0.0f, a1 = 0.0f;
    for (int m = 0; m < 32; ++m) {
        a0 += nz[m * D_DIM + e0];
        a1 += nz[m * D_DIM + e1];
    }
    float v0 = fmaf(a0, 0.125f, s0);
    float v1 = fmaf(a1, 0.125f, s1);

    const int m_ = t >> 3;
    const int k_ = t & 7;
    const int k0 = e0 >> 6;
    const int k1 = e1 >> 6;

    for (int it = 1; it < miter; ++it) {
        float ss0 = v0 * v0, ss1 = v1 * v1;
        #pragma unroll
        for (int off = 32; off >= 1; off >>= 1) {
            ss0 += __shfl_xor(ss0, off);
            ss1 += __shfl_xor(ss1, off);
        }
        v0 *= 1.0f / fmaxf(sqrtf(ss0), 1e-12f);
        v1 *= 1.0f / fmaxf(sqrtf(ss1), 1e-12f);
        u[e0] = v0;
        u[e1] = v1;
        __syncthreads();

        float dot = 0.0f;
        const int base = m_ * D_DIM + k_ * 64;
        const int ub = k_ * 64;
        #pragma unroll
        for (int i = 0; i < 64; ++i) {
            const int hh = (i + lane) & 63;
            dot = fmaf(nz[base + hh], u[ub + hh], dot);
        }
        float mx = dot;
        mx = fmaxf(mx, __shfl_xor(mx, 1));
        mx = fmaxf(mx, __shfl_xor(mx, 2));
        mx = fmaxf(mx, __shfl_xor(mx, 4));
        const float pe = __expf(dot - mx);
        float psum = pe;
        psum += __shfl_xor(psum, 1);
        psum += __shfl_xor(psum, 2);
        psum += __shfl_xor(psum, 4);
        p[t] = pe / psum;
        __syncthreads();

        a0 = 0.0f; a1 = 0.0f;
        for (int m = 0; m < 32; ++m) {
            a0 = fmaf(nz[m * D_DIM + e0], p[m * 8 + k0], a0);
            a1 = fmaf(nz[m * D_DIM + e1], p[m * 8 + k1], a1);
        }
        v0 = s0 + a0;
        v1 = s1 + a1;
        __syncthreads();
    }

    out[(size_t)site * D_DIM + e0] = fmaxf(v0, 0.0f);
    out[(size_t)site * D_DIM + e1] = fmaxf(v1, 0.0f);
}

extern "C" void kernel_launch(void* const* d_in, const int* in_sizes, int n_in,
                              void* d_out, int out_size, void* d_ws, size_t ws_size,
                              hipStream_t stream) {
    const float* self_v  = (const float*)d_in[0];   // [6400,512]
    const float* neigh_v = (const float*)d_in[1];   // [204800,512]
    const float* W1      = (const float*)d_in[2];   // [512,512]
    const float* b1      = (const float*)d_in[3];   // [512]
    const int*   miter   = (const int*)d_in[4];
    float* out = (float*)d_out;

    const int sites = in_sizes[0] / D_DIM;          // 6400
    const int nrows = in_sizes[1] / D_DIM;          // 204800

    short* nz = (short*)d_ws;                       // [nrows,512] bf16
    short* s  = nz + (size_t)nrows * D_DIM;         // [sites,512] bf16
    short* Wb = s + (size_t)sites * D_DIM;          // [512,512] bf16

    wconv<<<dim3(D_DIM * D_DIM / (256 * 8)), dim3(256), 0, stream>>>(W1, Wb);
    gemm_mfma<<<dim3(nrows / 128, D_DIM / 128), dim3(256), 0, stream>>>(neigh_v, Wb, b1, nz);
    gemm_mfma<<<dim3(sites / 128, D_DIM / 128), dim3(256), 0, stream>>>(self_v, Wb, b1, s);
    routing_iters<<<dim3(sites), dim3(256), 0, stream>>>(nz, s, miter, out);
}

// Round 3
// 442.155 us; speedup vs baseline: 3.2159x; 1.1801x over previous
//
#include <hip/hip_runtime.h>
#include <hip/hip_bf16.h>

// B=128, N=50, NB=32, K=8, H=64, D=512. sites=6400, neighbor rows=204800.
// Phase 0: W1 fp32 -> bf16 (once per call, into ws).
// Phase 1: Z = l2norm_g64(relu(X @ W^T + b)) via bf16 MFMA, fp32 accum; Z bf16.
//          A staged fp32 -> LDS via global_load_lds (16B), converted at frag read.
//          Grid (cols, panels) so same-panel column blocks are adjacent (L3 reuse).
// Phase 2: routing iterations per site, nz [32][512] in LDS as fp32.

#define D_DIM 512

typedef __attribute__((ext_vector_type(8))) short short8;
typedef __attribute__((ext_vector_type(4))) float f32x4;

__device__ __forceinline__ short f2bf(float f) {
    __bf16 b = (__bf16)f;
    return __builtin_bit_cast(short, b);
}
__device__ __forceinline__ float bf2f(short s) {
    unsigned u = ((unsigned)(unsigned short)s) << 16;
    return __builtin_bit_cast(float, u);
}

__device__ __forceinline__ void gload_lds16(const void* g, void* l) {
    __builtin_amdgcn_global_load_lds(
        (const __attribute__((address_space(1))) void*)g,
        (__attribute__((address_space(3))) void*)l, 16, 0, 0);
}

__global__ __launch_bounds__(256) void wconv(const float* __restrict__ W,
                                             short* __restrict__ Wb) {
    const int i = (blockIdx.x * 256 + threadIdx.x) * 8;
    const float4 v0 = *reinterpret_cast<const float4*>(W + i);
    const float4 v1 = *reinterpret_cast<const float4*>(W + i + 4);
    short8 o;
    o[0] = f2bf(v0.x); o[1] = f2bf(v0.y); o[2] = f2bf(v0.z); o[3] = f2bf(v0.w);
    o[4] = f2bf(v1.x); o[5] = f2bf(v1.y); o[6] = f2bf(v1.z); o[7] = f2bf(v1.w);
    *reinterpret_cast<short8*>(Wb + i) = o;
}

// 128x128 tile, BK=64, 8 K-steps. 256 threads = 4 waves (2x2), wave = 64x64.
// LDS: lA [128][64] fp32 (32 KB) via global_load_lds; lB [128][64] bf16 (16 KB).
__global__ __launch_bounds__(256, 3) void gemm_mfma(
    const float* __restrict__ A,    // [R,512] fp32
    const short* __restrict__ Wb,   // [512,512] bf16 bits
    const float* __restrict__ bias, // [512]
    short* __restrict__ Z)          // [R,512] bf16 bits, l2-normalized groups
{
    __shared__ float lA[128 * 64];  // 32 KB
    __shared__ short lB[128 * 64];  // 16 KB

    const int t = threadIdx.x;
    const int lane = t & 63;
    const int wid = t >> 6;
    const int col0 = blockIdx.x * 128;                 // x = column tile (0..3)
    const size_t row0 = (size_t)blockIdx.y * 128;      // y = row panel
    const int wr = (wid >> 1) * 64;
    const int wc = (wid & 1) * 64;

    // Staging: A = 32 chunks of 1024B (4 rows each); B = 16 chunks (8 rows each).
    // Wave w handles A chunks [8w,8w+8) and B chunks [4w,4w+4).
    auto stage = [&](int k0) {
        #pragma unroll
        for (int i = 0; i < 8; ++i) {
            const int c = wid * 8 + i;
            const float* gp = A + (row0 + c * 4 + (lane >> 4)) * D_DIM + k0 + (lane & 15) * 4;
            gload_lds16(gp, lA + c * 256);
        }
        #pragma unroll
        for (int i = 0; i < 4; ++i) {
            const int c = wid * 4 + i;
            const short* gp = Wb + (size_t)(col0 + c * 8 + (lane >> 3)) * D_DIM + k0 + (lane & 7) * 8;
            gload_lds16(gp, lB + c * 512);
        }
    };

    f32x4 acc[4][4] = {};

    auto compute = [&]() {
        #pragma unroll
        for (int kh = 0; kh < 2; ++kh) {
            const int slot = kh * 4 + (lane >> 4);     // 0..7 (8 bf16 / 8 fp32 each)
            short8 af[4], bfr[4];
            #pragma unroll
            for (int m = 0; m < 4; ++m) {
                const int arow = wr + m * 16 + (lane & 15);
                const float* ap = lA + arow * 64 + slot * 8;
                const f32x4 a0 = *reinterpret_cast<const f32x4*>(ap);
                const f32x4 a1 = *reinterpret_cast<const f32x4*>(ap + 4);
                short8 f;
                f[0] = f2bf(a0[0]); f[1] = f2bf(a0[1]);
                f[2] = f2bf(a0[2]); f[3] = f2bf(a0[3]);
                f[4] = f2bf(a1[0]); f[5] = f2bf(a1[1]);
                f[6] = f2bf(a1[2]); f[7] = f2bf(a1[3]);
                af[m] = f;
            }
            #pragma unroll
            for (int n = 0; n < 4; ++n) {
                const int brow = wc + n * 16 + (lane & 15);
                bfr[n] = *reinterpret_cast<const short8*>(lB + brow * 64 + slot * 8);
            }
            #pragma unroll
            for (int m = 0; m < 4; ++m)
                #pragma unroll
                for (int n = 0; n < 4; ++n)
                    acc[m][n] = __builtin_amdgcn_mfma_f32_16x16x32_bf16(
                        af[m], bfr[n], acc[m][n], 0, 0, 0);
        }
    };

    for (int tk = 0; tk < 8; ++tk) {
        stage(tk * 64);
        __syncthreads();            // compiler drains vmcnt before s_barrier
        compute();
        __syncthreads();
    }

    // Epilogue: bias + ReLU + l2norm over the wave's 64-col capsule group.
    const int cbase = col0 + wc + (lane & 15);
    const int g = lane >> 4;
    float bcol[4];
    #pragma unroll
    for (int n = 0; n < 4; ++n) bcol[n] = bias[cbase + n * 16];

    #pragma unroll
    for (int m = 0; m < 4; ++m) {
        #pragma unroll
        for (int r = 0; r < 4; ++r) {
            float v[4];
            float ss = 0.0f;
            #pragma unroll
            for (int n = 0; n < 4; ++n) {
                v[n] = fmaxf(acc[m][n][r] + bcol[n], 0.0f);
                ss = fmaf(v[n], v[n], ss);
            }
            ss += __shfl_xor(ss, 1);
            ss += __shfl_xor(ss, 2);
            ss += __shfl_xor(ss, 4);
            ss += __shfl_xor(ss, 8);
            const float inv = 1.0f / fmaxf(sqrtf(ss), 1e-12f);
            const size_t orow = row0 + wr + m * 16 + g * 4 + r;
            #pragma unroll
            for (int n = 0; n < 4; ++n)
                Z[orow * D_DIM + cbase + n * 16] = f2bf(v[n] * inv);
        }
    }
}

// One block per (b,n) site. nz [32][512] fp32 in LDS (64 KB), sourced from bf16.
__global__ __launch_bounds__(256) void routing_iters(
    const short* __restrict__ NZ,   // [sites,32,512] bf16 normalized
    const short* __restrict__ S,    // [sites,512] bf16 normalized
    const int* __restrict__ miter_ptr,
    float* __restrict__ out)        // [sites,512]
{
    __shared__ float nz[32 * 512];
    __shared__ float u[512];
    __shared__ float p[256];

    const int site = blockIdx.x;
    const int t = threadIdx.x;
    const int lane = t & 63;

    const short8* src = reinterpret_cast<const short8*>(NZ + (size_t)site * 32 * D_DIM);
    #pragma unroll
    for (int i = 0; i < 8; ++i) {
        const short8 c = src[t + 256 * i];
        const int base = (t + 256 * i) * 8;
        float4 f0, f1;
        f0.x = bf2f(c[0]); f0.y = bf2f(c[1]); f0.z = bf2f(c[2]); f0.w = bf2f(c[3]);
        f1.x = bf2f(c[4]); f1.y = bf2f(c[5]); f1.z = bf2f(c[6]); f1.w = bf2f(c[7]);
        *reinterpret_cast<float4*>(nz + base) = f0;
        *reinterpret_cast<float4*>(nz + base + 4) = f1;
    }

    const int e0 = t, e1 = t + 256;
    const float s0 = bf2f(S[(size_t)site * D_DIM + e0]);
    const float s1 = bf2f(S[(size_t)site * D_DIM + e1]);
    const int miter = *miter_ptr;

    __syncthreads();

    float a0 = 0.0f, a1 = 0.0f;
    for (int m = 0; m < 32; ++m) {
        a0 += nz[m * D_DIM + e0];
        a1 += nz[m * D_DIM + e1];
    }
    float v0 = fmaf(a0, 0.125f, s0);
    float v1 = fmaf(a1, 0.125f, s1);

    const int m_ = t >> 3;
    const int k_ = t & 7;
    const int k0 = e0 >> 6;
    const int k1 = e1 >> 6;

    for (int it = 1; it < miter; ++it) {
        float ss0 = v0 * v0, ss1 = v1 * v1;
        #pragma unroll
        for (int off = 32; off >= 1; off >>= 1) {
            ss0 += __shfl_xor(ss0, off);
            ss1 += __shfl_xor(ss1, off);
        }
        v0 *= 1.0f / fmaxf(sqrtf(ss0), 1e-12f);
        v1 *= 1.0f / fmaxf(sqrtf(ss1), 1e-12f);
        u[e0] = v0;
        u[e1] = v1;
        __syncthreads();

        float dot = 0.0f;
        const int base = m_ * D_DIM + k_ * 64;
        const int ub = k_ * 64;
        #pragma unroll
        for (int i = 0; i < 64; ++i) {
            const int hh = (i + lane) & 63;
            dot = fmaf(nz[base + hh], u[ub + hh], dot);
        }
        float mx = dot;
        mx = fmaxf(mx, __shfl_xor(mx, 1));
        mx = fmaxf(mx, __shfl_xor(mx, 2));
        mx = fmaxf(mx, __shfl_xor(mx, 4));
        const float pe = __expf(dot - mx);
        float psum = pe;
        psum += __shfl_xor(psum, 1);
        psum += __shfl_xor(psum, 2);
        psum += __shfl_xor(psum, 4);
        p[t] = pe / psum;
        __syncthreads();

        a0 = 0.0f; a1 = 0.0f;
        for (int m = 0; m < 32; ++m) {
            a0 = fmaf(nz[m * D_DIM + e0], p[m * 8 + k0], a0);
            a1 = fmaf(nz[m * D_DIM + e1], p[m * 8 + k1], a1);
        }
        v0 = s0 + a0;
        v1 = s1 + a1;
        __syncthreads();
    }

    out[(size_t)site * D_DIM + e0] = fmaxf(v0, 0.0f);
    out[(size_t)site * D_DIM + e1] = fmaxf(v1, 0.0f);
}

extern "C" void kernel_launch(void* const* d_in, const int* in_sizes, int n_in,
                              void* d_out, int out_size, void* d_ws, size_t ws_size,
                              hipStream_t stream) {
    const float* self_v  = (const float*)d_in[0];   // [6400,512]
    const float* neigh_v = (const float*)d_in[1];   // [204800,512]
    const float* W1      = (const float*)d_in[2];   // [512,512]
    const float* b1      = (const float*)d_in[3];   // [512]
    const int*   miter   = (const int*)d_in[4];
    float* out = (float*)d_out;

    const int sites = in_sizes[0] / D_DIM;          // 6400
    const int nrows = in_sizes[1] / D_DIM;          // 204800

    short* nz = (short*)d_ws;                       // [nrows,512] bf16
    short* s  = nz + (size_t)nrows * D_DIM;         // [sites,512] bf16
    short* Wb = s + (size_t)sites * D_DIM;          // [512,512] bf16

    wconv<<<dim3(D_DIM * D_DIM / (256 * 8)), dim3(256), 0, stream>>>(W1, Wb);
    // x = column tile (4), y = row panel -> same-panel blocks adjacent in dispatch
    gemm_mfma<<<dim3(D_DIM / 128, nrows / 128), dim3(256), 0, stream>>>(neigh_v, Wb, b1, nz);
    gemm_mfma<<<dim3(D_DIM / 128, sites / 128), dim3(256), 0, stream>>>(self_v, Wb, b1, s);
    routing_iters<<<dim3(sites), dim3(256), 0, stream>>>(nz, s, miter, out);
}

// Round 4
// 307.306 us; speedup vs baseline: 4.6270x; 1.4388x over previous
//
#include <hip/hip_runtime.h>
#include <hip/hip_bf16.h>

// B=128, N=50, NB=32, K=8, H=64, D=512. sites=6400, neighbor rows=204800.
// GEMM: BM=64 x BN=512 (full width) per block -> A read exactly once from HBM.
// LDS linear-dest staging + pre-swizzled global source, swizzled fragment reads.
// Routing: per-site iterations, nz fp32 in LDS, vectorized + staggered reads.

#define D_DIM 512

typedef __attribute__((ext_vector_type(8))) short short8;
typedef __attribute__((ext_vector_type(4))) float f32x4;

static __device__ __forceinline__ short f2bf(float f) {
    __bf16 b = (__bf16)f;
    return __builtin_bit_cast(short, b);
}
static __device__ __forceinline__ float bf2f(short s) {
    unsigned u = ((unsigned)(unsigned short)s) << 16;
    return __builtin_bit_cast(float, u);
}
static __device__ __forceinline__ void gload_lds16(const void* g, void* l) {
    __builtin_amdgcn_global_load_lds(
        (const __attribute__((address_space(1))) void*)g,
        (__attribute__((address_space(3))) void*)l, 16, 0, 0);
}

__global__ __launch_bounds__(256) void wconv(const float* __restrict__ W,
                                             short* __restrict__ Wb) {
    const int i = (blockIdx.x * 256 + threadIdx.x) * 8;
    const float4 v0 = *reinterpret_cast<const float4*>(W + i);
    const float4 v1 = *reinterpret_cast<const float4*>(W + i + 4);
    short8 o;
    o[0] = f2bf(v0.x); o[1] = f2bf(v0.y); o[2] = f2bf(v0.z); o[3] = f2bf(v0.w);
    o[4] = f2bf(v1.x); o[5] = f2bf(v1.y); o[6] = f2bf(v1.z); o[7] = f2bf(v1.w);
    *reinterpret_cast<short8*>(Wb + i) = o;
}

// 64x512 tile, BK=64, 8 K-steps. 256 threads = 4 waves; wave w -> 64 rows x cols [128w,128w+128).
// lA [64][64] bf16 (8 KB, reg-staged, cvt at staging); lB [512][64] bf16 (64 KB, global_load_lds).
// Swizzle: LDS[row][x] holds global 16B-chunk x^(row&7); reads use slot^(row&7). Dests linear.
__global__ __launch_bounds__(256, 2) void gemm_mfma(
    const float* __restrict__ A,    // [R,512] fp32
    const short* __restrict__ Wb,   // [512,512] bf16 bits
    const float* __restrict__ bias, // [512]
    short* __restrict__ Z)          // [R,512] bf16 bits, l2-normalized 64-groups
{
    __shared__ short lA[64 * 64];    // 8 KB
    __shared__ short lB[512 * 64];   // 64 KB

    const int t = threadIdx.x;
    const int lane = t & 63;
    const int wid = t >> 6;
    const size_t row0 = (size_t)blockIdx.x * 64;
    const int wc = wid * 128;

    // A staging: thread t owns LDS 16B-slots {t, t+256}. slot s: row=s>>3, col x=s&7,
    // global col chunk g = x ^ (row&7). Rows for the two slots differ by 32 -> same (row&7).
    const int arow0 = t >> 3;             // 0..31
    const int agcol = (t & 7) ^ (arow0 & 7);
    float4 ra[4];

    auto loadA = [&](int k0) {
        const float* p0 = A + (row0 + arow0) * D_DIM + k0 + agcol * 8;
        const float* p1 = A + (row0 + arow0 + 32) * D_DIM + k0 + agcol * 8;
        ra[0] = *reinterpret_cast<const float4*>(p0);
        ra[1] = *reinterpret_cast<const float4*>(p0 + 4);
        ra[2] = *reinterpret_cast<const float4*>(p1);
        ra[3] = *reinterpret_cast<const float4*>(p1 + 4);
    };
    auto writeA = [&]() {
        short8 c0, c1;
        c0[0] = f2bf(ra[0].x); c0[1] = f2bf(ra[0].y); c0[2] = f2bf(ra[0].z); c0[3] = f2bf(ra[0].w);
        c0[4] = f2bf(ra[1].x); c0[5] = f2bf(ra[1].y); c0[6] = f2bf(ra[1].z); c0[7] = f2bf(ra[1].w);
        c1[0] = f2bf(ra[2].x); c1[1] = f2bf(ra[2].y); c1[2] = f2bf(ra[2].z); c1[3] = f2bf(ra[2].w);
        c1[4] = f2bf(ra[3].x); c1[5] = f2bf(ra[3].y); c1[6] = f2bf(ra[3].z); c1[7] = f2bf(ra[3].w);
        *reinterpret_cast<short8*>(lA + t * 8) = c0;
        *reinterpret_cast<short8*>(lA + (t + 256) * 8) = c1;
    };
    // B staging: 64 chunks of 1024B (8 rows x 8 slots); wave w -> chunks [16w,16w+16).
    auto stageB = [&](int k0) {
        #pragma unroll
        for (int i = 0; i < 16; ++i) {
            const int c = wid * 16 + i;
            const int brow = c * 8 + (lane >> 3);
            const int g = (lane & 7) ^ (brow & 7);
            gload_lds16(Wb + (size_t)brow * D_DIM + k0 + g * 8, lB + c * 512);
        }
    };

    f32x4 acc[4][8] = {};

    auto compute = [&]() {
        #pragma unroll
        for (int kh = 0; kh < 2; ++kh) {
            const int slot = kh * 4 + (lane >> 4);    // 0..7 (16B k-chunks)
            short8 af[4], bfr[8];
            #pragma unroll
            for (int m = 0; m < 4; ++m) {
                const int arow = m * 16 + (lane & 15);
                af[m] = *reinterpret_cast<const short8*>(
                    lA + arow * 64 + ((slot ^ (arow & 7)) * 8));
            }
            #pragma unroll
            for (int n = 0; n < 8; ++n) {
                const int brow = wc + n * 16 + (lane & 15);
                bfr[n] = *reinterpret_cast<const short8*>(
                    lB + brow * 64 + ((slot ^ (brow & 7)) * 8));
            }
            #pragma unroll
            for (int m = 0; m < 4; ++m)
                #pragma unroll
                for (int n = 0; n < 8; ++n)
                    acc[m][n] = __builtin_amdgcn_mfma_f32_16x16x32_bf16(
                        af[m], bfr[n], acc[m][n], 0, 0, 0);
        }
    };

    loadA(0);
    for (int tk = 0; tk < 8; ++tk) {
        writeA();
        stageB(tk * 64);
        if (tk < 7) loadA((tk + 1) * 64);   // issue next A before the drain
        __syncthreads();                     // staging for tk visible
        compute();
        if (tk < 7) __syncthreads();         // done reading before next write
    }

    // Epilogue: bias + ReLU + l2norm per 64-col group (n 0..3 and n 4..7).
    const int cb = wc + (lane & 15);
    float bcol[8];
    #pragma unroll
    for (int n = 0; n < 8; ++n) bcol[n] = bias[cb + n * 16];

    #pragma unroll
    for (int m = 0; m < 4; ++m) {
        #pragma unroll
        for (int r = 0; r < 4; ++r) {
            float v[8];
            float ssa = 0.0f, ssb = 0.0f;
            #pragma unroll
            for (int n = 0; n < 4; ++n) {
                v[n] = fmaxf(acc[m][n][r] + bcol[n], 0.0f);
                ssa = fmaf(v[n], v[n], ssa);
            }
            #pragma unroll
            for (int n = 4; n < 8; ++n) {
                v[n] = fmaxf(acc[m][n][r] + bcol[n], 0.0f);
                ssb = fmaf(v[n], v[n], ssb);
            }
            ssa += __shfl_xor(ssa, 1); ssb += __shfl_xor(ssb, 1);
            ssa += __shfl_xor(ssa, 2); ssb += __shfl_xor(ssb, 2);
            ssa += __shfl_xor(ssa, 4); ssb += __shfl_xor(ssb, 4);
            ssa += __shfl_xor(ssa, 8); ssb += __shfl_xor(ssb, 8);
            const float inva = 1.0f / fmaxf(sqrtf(ssa), 1e-12f);
            const float invb = 1.0f / fmaxf(sqrtf(ssb), 1e-12f);
            const size_t orow = row0 + m * 16 + (lane >> 4) * 4 + r;
            #pragma unroll
            for (int n = 0; n < 4; ++n)
                Z[orow * D_DIM + cb + n * 16] = f2bf(v[n] * inva);
            #pragma unroll
            for (int n = 4; n < 8; ++n)
                Z[orow * D_DIM + cb + n * 16] = f2bf(v[n] * invb);
        }
    }
}

// One block per site. nz [32][512] fp32 in LDS. Thread owns elems {2t, 2t+1} (same 64-group).
__global__ __launch_bounds__(256, 2) void routing_iters(
    const short* __restrict__ NZ,   // [sites,32,512] bf16 normalized
    const short* __restrict__ S,    // [sites,512] bf16 normalized
    const int* __restrict__ miter_ptr,
    float* __restrict__ out)        // [sites,512]
{
    __shared__ __align__(16) float nz[32 * 512];
    __shared__ __align__(16) float u[512];
    __shared__ float p[256];

    const int site = blockIdx.x;
    const int t = threadIdx.x;
    const int lane = t & 63;

    const short8* src = reinterpret_cast<const short8*>(NZ + (size_t)site * 32 * D_DIM);
    #pragma unroll
    for (int i = 0; i < 8; ++i) {
        const short8 c = src[t + 256 * i];
        const int base = (t + 256 * i) * 8;
        float4 f0, f1;
        f0.x = bf2f(c[0]); f0.y = bf2f(c[1]); f0.z = bf2f(c[2]); f0.w = bf2f(c[3]);
        f1.x = bf2f(c[4]); f1.y = bf2f(c[5]); f1.z = bf2f(c[6]); f1.w = bf2f(c[7]);
        *reinterpret_cast<float4*>(nz + base) = f0;
        *reinterpret_cast<float4*>(nz + base + 4) = f1;
    }

    const int e = 2 * t;
    const int kg = t >> 5;                  // capsule group of both owned elems
    const short2 sv = *reinterpret_cast<const short2*>(S + (size_t)site * D_DIM + e);
    const float s0 = bf2f(sv.x), s1 = bf2f(sv.y);
    const int miter = *miter_ptr;

    __syncthreads();

    // Iteration 0: p uniform = 1/8.
    float a0 = 0.0f, a1 = 0.0f;
    for (int m = 0; m < 32; ++m) {
        const float2 z = *reinterpret_cast<const float2*>(nz + m * D_DIM + e);
        a0 += z.x; a1 += z.y;
    }
    float v0 = fmaf(a0, 0.125f, s0);
    float v1 = fmaf(a1, 0.125f, s1);

    const int m_ = t >> 3;
    const int k_ = t & 7;

    for (int it = 1; it < miter; ++it) {
        // l2norm of u per 64-group: group spans 32 consecutive threads (one wave half).
        float ss = fmaf(v0, v0, v1 * v1);
        #pragma unroll
        for (int off = 16; off >= 1; off >>= 1) ss += __shfl_xor(ss, off);
        const float inv = 1.0f / fmaxf(sqrtf(ss), 1e-12f);
        v0 *= inv; v1 *= inv;
        *reinterpret_cast<float2*>(u + e) = make_float2(v0, v1);
        __syncthreads();

        // p[m_][k_] = dot(nz[m_, 64k_ : +64], u[64k_ : +64]); staggered float4 reads.
        const float4* nz4 = reinterpret_cast<const float4*>(nz + m_ * D_DIM + k_ * 64);
        const float4* u4  = reinterpret_cast<const float4*>(u + k_ * 64);
        float dot = 0.0f;
        #pragma unroll
        for (int i = 0; i < 16; ++i) {
            const int hh = (i + lane) & 15;
            const float4 a = nz4[hh];
            const float4 b = u4[hh];
            dot += a.x * b.x + a.y * b.y + a.z * b.z + a.w * b.w;
        }
        float mx = dot;
        mx = fmaxf(mx, __shfl_xor(mx, 1));
        mx = fmaxf(mx, __shfl_xor(mx, 2));
        mx = fmaxf(mx, __shfl_xor(mx, 4));
        const float pe = __expf(dot - mx);
        float psum = pe;
        psum += __shfl_xor(psum, 1);
        psum += __shfl_xor(psum, 2);
        psum += __shfl_xor(psum, 4);
        p[t] = pe / psum;
        __syncthreads();

        // u = s + sum_m nz[m]*p[m,kg]
        a0 = 0.0f; a1 = 0.0f;
        for (int m = 0; m < 32; ++m) {
            const float2 z = *reinterpret_cast<const float2*>(nz + m * D_DIM + e);
            const float pm = p[m * 8 + kg];
            a0 = fmaf(z.x, pm, a0);
            a1 = fmaf(z.y, pm, a1);
        }
        v0 = s0 + a0;
        v1 = s1 + a1;
        __syncthreads();
    }

    float2 o = make_float2(fmaxf(v0, 0.0f), fmaxf(v1, 0.0f));
    *reinterpret_cast<float2*>(out + (size_t)site * D_DIM + e) = o;
}

extern "C" void kernel_launch(void* const* d_in, const int* in_sizes, int n_in,
                              void* d_out, int out_size, void* d_ws, size_t ws_size,
                              hipStream_t stream) {
    const float* self_v  = (const float*)d_in[0];   // [6400,512]
    const float* neigh_v = (const float*)d_in[1];   // [204800,512]
    const float* W1      = (const float*)d_in[2];   // [512,512]
    const float* b1      = (const float*)d_in[3];   // [512]
    const int*   miter   = (const int*)d_in[4];
    float* out = (float*)d_out;

    const int sites = in_sizes[0] / D_DIM;          // 6400
    const int nrows = in_sizes[1] / D_DIM;          // 204800

    short* nz = (short*)d_ws;                       // [nrows,512] bf16
    short* s  = nz + (size_t)nrows * D_DIM;         // [sites,512] bf16
    short* Wb = s + (size_t)sites * D_DIM;          // [512,512] bf16

    wconv<<<dim3(D_DIM * D_DIM / (256 * 8)), dim3(256), 0, stream>>>(W1, Wb);
    gemm_mfma<<<dim3(nrows / 64), dim3(256), 0, stream>>>(neigh_v, Wb, b1, nz);
    gemm_mfma<<<dim3(sites / 64), dim3(256), 0, stream>>>(self_v, Wb, b1, s);
    routing_iters<<<dim3(sites), dim3(256), 0, stream>>>(nz, s, miter, out);
}

// Round 5
// 283.842 us; speedup vs baseline: 5.0095x; 1.0827x over previous
//
#include <hip/hip_runtime.h>
#include <hip/hip_bf16.h>

// B=128, N=50, NB=32, K=8, H=64, D=512. sites=6400, neighbor rows=204800.
// Fused design:
//   wconv:   W1 fp32 -> bf16.
//   self:    gemm_route<false>: s = l2norm_g64(relu(self @ W^T + b)) -> HBM bf16.
//   fused:   gemm_route<true>:  per block, 64 neighbor rows (=2 sites) GEMM into
//            LDS zbuf (bf16), then 3 routing iterations in-block, write fp32 out.
//            nz never touches HBM.
// GEMM: BM=64 x BN=512 x BK=32, double-buffered LDS, 1 barrier/K-step,
// issue-early staging, rotation swizzle p=(s+(r>>1))&3 (conflict-free).

#define D_DIM 512
#define BM 64
#define BK 32
#define KSTEPS (D_DIM / BK)

typedef __attribute__((ext_vector_type(8))) short short8;
typedef __attribute__((ext_vector_type(4))) short short4v;
typedef __attribute__((ext_vector_type(4))) float f32x4;

static __device__ __forceinline__ short f2bf(float f) {
    __bf16 b = (__bf16)f;
    return __builtin_bit_cast(short, b);
}
static __device__ __forceinline__ float bf2f(short s) {
    unsigned u = ((unsigned)(unsigned short)s) << 16;
    return __builtin_bit_cast(float, u);
}
static __device__ __forceinline__ void gload_lds16(const void* g, void* l) {
    __builtin_amdgcn_global_load_lds(
        (const __attribute__((address_space(1))) void*)g,
        (__attribute__((address_space(3))) void*)l, 16, 0, 0);
}

__global__ __launch_bounds__(256) void wconv(const float* __restrict__ W,
                                             short* __restrict__ Wb) {
    const int i = (blockIdx.x * 256 + threadIdx.x) * 8;
    const float4 v0 = *reinterpret_cast<const float4*>(W + i);
    const float4 v1 = *reinterpret_cast<const float4*>(W + i + 4);
    short8 o;
    o[0] = f2bf(v0.x); o[1] = f2bf(v0.y); o[2] = f2bf(v0.z); o[3] = f2bf(v0.w);
    o[4] = f2bf(v1.x); o[5] = f2bf(v1.y); o[6] = f2bf(v1.z); o[7] = f2bf(v1.w);
    *reinterpret_cast<short8*>(Wb + i) = o;
}

// 256 threads = 4 waves; wave w computes 64 rows x cols [128w, 128w+128).
// LDS: lA[2][64x32 bf16] (8 KB) reg-staged; lB[2][512x32 bf16] (64 KB) via
// global_load_lds. Row = 64 B = 4 slots of 16 B; physical slot p=(s+(r>>1))&3.
template <bool FUSED>
__global__ __launch_bounds__(256, 2) void gemm_route(
    const float* __restrict__ A,     // [R,512] fp32
    const short* __restrict__ Wb,    // [512,512] bf16
    const float* __restrict__ bias,  // [512]
    short* __restrict__ Zs,          // !FUSED: s output bf16
    const short* __restrict__ S,     // FUSED: s input bf16
    const int* __restrict__ miter_ptr,
    float* __restrict__ out)         // FUSED: [sites,512] fp32
{
    __shared__ __align__(16) char smem[73728];
    short* const lA = (short*)smem;            // [2][2048]
    short* const lB = (short*)(smem + 8192);   // [2][16384]

    const int t = threadIdx.x;
    const int lane = t & 63;
    const int wid = t >> 6;
    const size_t row0 = (size_t)blockIdx.x * BM;
    const int wc = wid * 128;

    // ---- A staging: thread t -> row ar, physical slot ap; global chunk ag.
    const int ar = t >> 2;                 // 0..63
    const int ap = t & 3;
    const int ag = (ap - (ar >> 1)) & 3;
    const float* const aPtr = A + (row0 + ar) * D_DIM + ag * 8;

    float4 ra0, ra1;
    auto loadAreg = [&](int k0) {
        ra0 = *reinterpret_cast<const float4*>(aPtr + k0);
        ra1 = *reinterpret_cast<const float4*>(aPtr + k0 + 4);
    };
    auto writeA = [&](int buf) {
        short8 c;
        c[0] = f2bf(ra0.x); c[1] = f2bf(ra0.y); c[2] = f2bf(ra0.z); c[3] = f2bf(ra0.w);
        c[4] = f2bf(ra1.x); c[5] = f2bf(ra1.y); c[6] = f2bf(ra1.z); c[7] = f2bf(ra1.w);
        *reinterpret_cast<short8*>(lA + buf * 2048 + ar * 32 + ap * 8) = c;
    };
    // ---- B staging: 32 chunks of 1024 B; wave w -> chunks [8w, 8w+8).
    auto stageB = [&](int k0, int buf) {
        #pragma unroll
        for (int i = 0; i < 8; ++i) {
            const int c = wid * 8 + i;
            const int r = c * 16 + (lane >> 2);
            const int p = lane & 3;
            const int g = (p - (r >> 1)) & 3;
            gload_lds16(Wb + (size_t)r * D_DIM + k0 + g * 8,
                        lB + buf * 16384 + c * 512);
        }
    };

    f32x4 acc[4][8] = {};

    auto compute = [&](int buf) {
        const int s_ = lane >> 4;          // k-chunk 0..3
        short8 af[4], bfr[8];
        #pragma unroll
        for (int m = 0; m < 4; ++m) {
            const int r = m * 16 + (lane & 15);
            af[m] = *reinterpret_cast<const short8*>(
                lA + buf * 2048 + r * 32 + ((s_ + (r >> 1)) & 3) * 8);
        }
        #pragma unroll
        for (int n = 0; n < 8; ++n) {
            const int r = wc + n * 16 + (lane & 15);
            bfr[n] = *reinterpret_cast<const short8*>(
                lB + buf * 16384 + r * 32 + ((s_ + (r >> 1)) & 3) * 8);
        }
        #pragma unroll
        for (int m = 0; m < 4; ++m)
            #pragma unroll
            for (int n = 0; n < 8; ++n)
                acc[m][n] = __builtin_amdgcn_mfma_f32_16x16x32_bf16(
                    af[m], bfr[n], acc[m][n], 0, 0, 0);
    };

    // ---- pipelined K loop: stage(t+1) issued before compute(t); 1 barrier/step.
    loadAreg(0);
    stageB(0, 0);
    writeA(0);
    __syncthreads();
    int cur = 0;
    for (int tk = 0; tk < KSTEPS; ++tk) {
        if (tk < KSTEPS - 1) {
            loadAreg((tk + 1) * BK);       // A first: writeA waits vmcnt(8) not 0
            stageB((tk + 1) * BK, cur ^ 1);
        }
        compute(cur);
        if (tk < KSTEPS - 1) writeA(cur ^ 1);
        __syncthreads();
        cur ^= 1;
    }

    // ---- epilogue: bias + ReLU + l2norm per 64-col group.
    short* const zbuf = (short*)(smem + 8192);   // aliases lB, free now
    const int cb = wc + (lane & 15);
    float bcol[8];
    #pragma unroll
    for (int n = 0; n < 8; ++n) bcol[n] = bias[cb + n * 16];

    #pragma unroll
    for (int m = 0; m < 4; ++m) {
        #pragma unroll
        for (int r = 0; r < 4; ++r) {
            float v[8];
            float ssa = 0.0f, ssb = 0.0f;
            #pragma unroll
            for (int n = 0; n < 4; ++n) {
                v[n] = fmaxf(acc[m][n][r] + bcol[n], 0.0f);
                ssa = fmaf(v[n], v[n], ssa);
            }
            #pragma unroll
            for (int n = 4; n < 8; ++n) {
                v[n] = fmaxf(acc[m][n][r] + bcol[n], 0.0f);
                ssb = fmaf(v[n], v[n], ssb);
            }
            ssa += __shfl_xor(ssa, 1); ssb += __shfl_xor(ssb, 1);
            ssa += __shfl_xor(ssa, 2); ssb += __shfl_xor(ssb, 2);
            ssa += __shfl_xor(ssa, 4); ssb += __shfl_xor(ssb, 4);
            ssa += __shfl_xor(ssa, 8); ssb += __shfl_xor(ssb, 8);
            const float inva = 1.0f / fmaxf(sqrtf(ssa), 1e-12f);
            const float invb = 1.0f / fmaxf(sqrtf(ssb), 1e-12f);
            const int orow = m * 16 + (lane >> 4) * 4 + r;   // 0..63
            if (FUSED) {
                #pragma unroll
                for (int n = 0; n < 4; ++n)
                    zbuf[orow * D_DIM + cb + n * 16] = f2bf(v[n] * inva);
                #pragma unroll
                for (int n = 4; n < 8; ++n)
                    zbuf[orow * D_DIM + cb + n * 16] = f2bf(v[n] * invb);
            } else {
                #pragma unroll
                for (int n = 0; n < 4; ++n)
                    Zs[(row0 + orow) * D_DIM + cb + n * 16] = f2bf(v[n] * inva);
                #pragma unroll
                for (int n = 4; n < 8; ++n)
                    Zs[(row0 + orow) * D_DIM + cb + n * 16] = f2bf(v[n] * invb);
            }
        }
    }

    if (!FUSED) return;
    __syncthreads();   // zbuf complete

    // ---- routing: 2 sites/block, 128 threads each; thread owns 4 elems.
    float* const scratch = (float*)smem;         // aliases lA (8 KB)
    const int tt = t & 127;
    const int ssid = t >> 7;
    const size_t site = (size_t)blockIdx.x * 2 + ssid;
    float* const u  = scratch + ssid * 512;
    float* const pp = scratch + 1024 + ssid * 256;
    const short* const zr = zbuf + ssid * 32 * D_DIM;

    const int e = tt * 4;
    const int go = tt >> 4;                  // capsule group of owned elems
    const short4v sv = *reinterpret_cast<const short4v*>(S + site * D_DIM + e);
    const float s0 = bf2f(sv[0]), s1 = bf2f(sv[1]), s2 = bf2f(sv[2]), s3 = bf2f(sv[3]);
    const int miter = *miter_ptr;

    float v0, v1, v2, v3;
    {   // iteration 0: p uniform 1/8
        float a0 = 0, a1 = 0, a2 = 0, a3 = 0;
        for (int m = 0; m < 32; ++m) {
            const short4v z = *reinterpret_cast<const short4v*>(zr + m * D_DIM + e);
            a0 += bf2f(z[0]); a1 += bf2f(z[1]); a2 += bf2f(z[2]); a3 += bf2f(z[3]);
        }
        v0 = fmaf(a0, 0.125f, s0); v1 = fmaf(a1, 0.125f, s1);
        v2 = fmaf(a2, 0.125f, s2); v3 = fmaf(a3, 0.125f, s3);
    }

    const int dm = tt >> 2;                  // neighbor for this thread's dots
    const int ka = (tt & 3) * 2;             // capsule pair

    for (int it = 1; it < miter; ++it) {
        // normalize u per 64-group (16-thread shfl groups, wave-aligned)
        float ssum = v0 * v0 + v1 * v1 + v2 * v2 + v3 * v3;
        ssum += __shfl_xor(ssum, 1);
        ssum += __shfl_xor(ssum, 2);
        ssum += __shfl_xor(ssum, 4);
        ssum += __shfl_xor(ssum, 8);
        const float inv = 1.0f / fmaxf(sqrtf(ssum), 1e-12f);
        v0 *= inv; v1 *= inv; v2 *= inv; v3 *= inv;
        *reinterpret_cast<float4*>(u + e) = make_float4(v0, v1, v2, v3);
        __syncthreads();

        // dots: p[dm][ka], p[dm][ka+1]; staggered reads (conflict-free octets)
        const short* const za = zr + dm * D_DIM + ka * 64;
        const float* const ua = u + ka * 64;
        float da = 0, db = 0;
        #pragma unroll
        for (int j = 0; j < 8; ++j) {
            const int jj = ((j + (tt & 7)) & 7) * 8;
            const short8 zva = *reinterpret_cast<const short8*>(za + jj);
            const short8 zvb = *reinterpret_cast<const short8*>(za + 64 + jj);
            const f32x4 uA0 = *reinterpret_cast<const f32x4*>(ua + jj);
            const f32x4 uA1 = *reinterpret_cast<const f32x4*>(ua + jj + 4);
            const f32x4 uB0 = *reinterpret_cast<const f32x4*>(ua + 64 + jj);
            const f32x4 uB1 = *reinterpret_cast<const f32x4*>(ua + 64 + jj + 4);
            #pragma unroll
            for (int q = 0; q < 4; ++q) {
                da = fmaf(bf2f(zva[q]), uA0[q], da);
                da = fmaf(bf2f(zva[q + 4]), uA1[q], da);
                db = fmaf(bf2f(zvb[q]), uB0[q], db);
                db = fmaf(bf2f(zvb[q + 4]), uB1[q], db);
            }
        }
        // softmax over 8 k (4 threads x 2 vals)
        float mx = fmaxf(da, db);
        mx = fmaxf(mx, __shfl_xor(mx, 1));
        mx = fmaxf(mx, __shfl_xor(mx, 2));
        const float ea = __expf(da - mx), eb = __expf(db - mx);
        float sm_ = ea + eb;
        sm_ += __shfl_xor(sm_, 1);
        sm_ += __shfl_xor(sm_, 2);
        const float rs = 1.0f / sm_;
        *reinterpret_cast<float2*>(pp + dm * 8 + ka) = make_float2(ea * rs, eb * rs);
        __syncthreads();

        // u = s + sum_m z[m]*p[m, go]
        float a0 = 0, a1 = 0, a2 = 0, a3 = 0;
        for (int m = 0; m < 32; ++m) {
            const short4v z = *reinterpret_cast<const short4v*>(zr + m * D_DIM + e);
            const float pm = pp[m * 8 + go];
            a0 = fmaf(bf2f(z[0]), pm, a0); a1 = fmaf(bf2f(z[1]), pm, a1);
            a2 = fmaf(bf2f(z[2]), pm, a2); a3 = fmaf(bf2f(z[3]), pm, a3);
        }
        v0 = s0 + a0; v1 = s1 + a1; v2 = s2 + a2; v3 = s3 + a3;
        // no barrier needed: next pp write is after next norm's barrier
    }

    *reinterpret_cast<float4*>(out + site * D_DIM + e) =
        make_float4(fmaxf(v0, 0.0f), fmaxf(v1, 0.0f), fmaxf(v2, 0.0f), fmaxf(v3, 0.0f));
}

extern "C" void kernel_launch(void* const* d_in, const int* in_sizes, int n_in,
                              void* d_out, int out_size, void* d_ws, size_t ws_size,
                              hipStream_t stream) {
    const float* self_v  = (const float*)d_in[0];   // [6400,512]
    const float* neigh_v = (const float*)d_in[1];   // [204800,512]
    const float* W1      = (const float*)d_in[2];   // [512,512]
    const float* b1      = (const float*)d_in[3];   // [512]
    const int*   miter   = (const int*)d_in[4];
    float* out = (float*)d_out;

    const int sites = in_sizes[0] / D_DIM;          // 6400
    const int nrows = in_sizes[1] / D_DIM;          // 204800

    short* s  = (short*)d_ws;                       // [sites,512] bf16
    short* Wb = s + (size_t)sites * D_DIM;          // [512,512] bf16

    wconv<<<dim3(D_DIM * D_DIM / (256 * 8)), dim3(256), 0, stream>>>(W1, Wb);
    gemm_route<false><<<dim3(sites / BM), dim3(256), 0, stream>>>(
        self_v, Wb, b1, s, nullptr, nullptr, nullptr);
    gemm_route<true><<<dim3(nrows / BM), dim3(256), 0, stream>>>(
        neigh_v, Wb, b1, nullptr, s, miter, out);
}

// Round 8
// 251.393 us; speedup vs baseline: 5.6561x; 1.1291x over previous
//
#include <hip/hip_runtime.h>
#include <hip/hip_bf16.h>

// B=128, N=50, NB=32, K=8, H=64, D=512. sites=6400, neighbor rows=204800.
// Fused: per block, 64 neighbor rows (=2 sites) GEMM (bf16 MFMA) into LDS zbuf
// (bf16), then 3 routing iterations in-block, write fp32 out. nz never hits HBM.
// Staging: SINGLE-TYPE global_load_lds for BOTH A (raw fp32) and B (bf16),
// counted s_waitcnt vmcnt(10) + raw s_barrier (m201 pattern) — loads stay in
// flight across barriers. A converted fp32->bf16 at fragment read.

#define D_DIM 512
#define BM 64
#define BK 32
#define KSTEPS 16

typedef __attribute__((ext_vector_type(8))) short short8;
typedef __attribute__((ext_vector_type(4))) short short4v;
typedef __attribute__((ext_vector_type(4))) float f32x4;

static __device__ __forceinline__ short f2bf(float f) {
    __bf16 b = (__bf16)f;
    return __builtin_bit_cast(short, b);
}
static __device__ __forceinline__ float bf2f(short s) {
    unsigned u = ((unsigned)(unsigned short)s) << 16;
    return __builtin_bit_cast(float, u);
}
static __device__ __forceinline__ void gload_lds16(const void* g, void* l) {
    __builtin_amdgcn_global_load_lds(
        (const __attribute__((address_space(1))) void*)g,
        (__attribute__((address_space(3))) void*)l, 16, 0, 0);
}

__global__ __launch_bounds__(256) void wconv(const float* __restrict__ W,
                                             short* __restrict__ Wb) {
    const int i = (blockIdx.x * 256 + threadIdx.x) * 8;
    const float4 v0 = *reinterpret_cast<const float4*>(W + i);
    const float4 v1 = *reinterpret_cast<const float4*>(W + i + 4);
    short8 o;
    o[0] = f2bf(v0.x); o[1] = f2bf(v0.y); o[2] = f2bf(v0.z); o[3] = f2bf(v0.w);
    o[4] = f2bf(v1.x); o[5] = f2bf(v1.y); o[6] = f2bf(v1.z); o[7] = f2bf(v1.w);
    *reinterpret_cast<short8*>(Wb + i) = o;
}

// 256 threads = 4 waves; wave w -> 64 rows x cols [128w,128w+128).
// lAf32[2]: [64][32] f32 (8 KB each) via DMA; row = 8 x 16B slots, phys
//   slot p=(g+2*(r&3))&7 (pair-preserving rotation -> 4-way read residual).
// lB[2]: [512][32] bf16 (32 KB each) via DMA; row = 4 x 16B slots, phys
//   slot p=(g+(r>>1))&3 (conflict-free reads).
template <bool FUSED>
__global__ __launch_bounds__(256, 2) void gemm_route(
    const float* __restrict__ A,     // [R,512] fp32
    const short* __restrict__ Wb,    // [512,512] bf16
    const float* __restrict__ bias,  // [512]
    short* __restrict__ Zs,          // !FUSED: s output bf16
    const short* __restrict__ S,     // FUSED: s input bf16
    const int* __restrict__ miter_ptr,
    float* __restrict__ out)         // FUSED: [sites,512] fp32
{
    __shared__ __align__(16) char smem[81920];
    float* const lAf32 = (float*)smem;           // [2][2048] f32  (16 KB)
    short* const lB = (short*)(smem + 16384);    // [2][16384] bf16 (64 KB)

    const int t = threadIdx.x;
    const int lane = t & 63;
    const int wid = t >> 6;
    const size_t row0 = (size_t)blockIdx.x * BM;
    const int wc = wid * 128;

    // hoisted scalars: issued before the first asm fence; ledger is robust to
    // their placement (each counted wait retires all but the newest 10).
    const int cb = wc + (lane & 15);
    float bcol[8];
    #pragma unroll
    for (int n = 0; n < 8; ++n) bcol[n] = bias[cb + n * 16];
    int miter = 0;
    if (FUSED) miter = *miter_ptr;

    // 10 DMAs per wave per step: 8 B-chunks + 2 A-chunks (1024 B each).
    auto stage = [&](int step, int buf) {
        const int k0 = (step < KSTEPS ? step : 0) * BK;
        #pragma unroll
        for (int i = 0; i < 8; ++i) {            // B: chunk = 16 rows x 64 B
            const int c = wid * 8 + i;
            const int r = c * 16 + (lane >> 2);
            const int g = ((lane & 3) - (r >> 1)) & 3;
            gload_lds16(Wb + (size_t)r * D_DIM + k0 + g * 8,
                        lB + buf * 16384 + c * 512);
        }
        #pragma unroll
        for (int i = 0; i < 2; ++i) {            // A: chunk = 8 rows x 128 B
            const int c = wid * 2 + i;
            const int r = c * 8 + (lane >> 3);
            const int g = ((lane & 7) - 2 * (r & 3)) & 7;
            gload_lds16(A + (row0 + r) * D_DIM + k0 + g * 4,
                        lAf32 + buf * 2048 + c * 256);
        }
    };

    f32x4 acc[4][8] = {};
    auto compute = [&](int buf) {
        const int q = lane >> 4;                 // k 16B-slot pair index
        short8 af[4], bfr[8];
        #pragma unroll
        for (int m = 0; m < 4; ++m) {
            const int r = m * 16 + (lane & 15);
            const float* ap = lAf32 + buf * 2048 + r * 32 + ((q + (r & 3)) & 3) * 8;
            const f32x4 a0 = *reinterpret_cast<const f32x4*>(ap);
            const f32x4 a1 = *reinterpret_cast<const f32x4*>(ap + 4);
            short8 f;
            f[0] = f2bf(a0[0]); f[1] = f2bf(a0[1]);
            f[2] = f2bf(a0[2]); f[3] = f2bf(a0[3]);
            f[4] = f2bf(a1[0]); f[5] = f2bf(a1[1]);
            f[6] = f2bf(a1[2]); f[7] = f2bf(a1[3]);
            af[m] = f;
        }
        #pragma unroll
        for (int n = 0; n < 8; ++n) {
            const int r = wc + n * 16 + (lane & 15);
            bfr[n] = *reinterpret_cast<const short8*>(
                lB + buf * 16384 + r * 32 + ((q + (r >> 1)) & 3) * 8);
        }
        #pragma unroll
        for (int m = 0; m < 4; ++m)
            #pragma unroll
            for (int n = 0; n < 8; ++n)
                acc[m][n] = __builtin_amdgcn_mfma_f32_16x16x32_bf16(
                    af[m], bfr[n], acc[m][n], 0, 0, 0);
    };

    // ---- pipeline: counted vmcnt, single op type, loads fly across barriers
    stage(0, 0);
    stage(1, 1);
    asm volatile("s_waitcnt vmcnt(10)" ::: "memory");   // stage0 (+scalars) done
    __builtin_amdgcn_s_barrier();
    #pragma unroll
    for (int tk = 0; tk < KSTEPS; ++tk) {
        compute(tk & 1);
        asm volatile("s_waitcnt lgkmcnt(0)" ::: "memory");  // reads consumed
        __builtin_amdgcn_s_barrier();                       // buf tk&1 free
        stage(tk + 2, tk & 1);                              // overwrite it
        asm volatile("s_waitcnt vmcnt(10)" ::: "memory");   // stage(tk+1) done
        __builtin_amdgcn_s_barrier();                       // visible to all
    }
    asm volatile("s_waitcnt vmcnt(0)" ::: "memory");        // drain tail junk
    __builtin_amdgcn_s_barrier();

    // ---- epilogue: bias + ReLU + l2norm per 64-col group; z as bf16.
    short* const zbuf = (short*)(smem + 16384);   // aliases lB (free now)
    #pragma unroll
    for (int m = 0; m < 4; ++m) {
        #pragma unroll
        for (int r = 0; r < 4; ++r) {
            float v[8];
            float ssa = 0.0f, ssb = 0.0f;
            #pragma unroll
            for (int n = 0; n < 4; ++n) {
                v[n] = fmaxf(acc[m][n][r] + bcol[n], 0.0f);
                ssa = fmaf(v[n], v[n], ssa);
            }
            #pragma unroll
            for (int n = 4; n < 8; ++n) {
                v[n] = fmaxf(acc[m][n][r] + bcol[n], 0.0f);
                ssb = fmaf(v[n], v[n], ssb);
            }
            ssa += __shfl_xor(ssa, 1); ssb += __shfl_xor(ssb, 1);
            ssa += __shfl_xor(ssa, 2); ssb += __shfl_xor(ssb, 2);
            ssa += __shfl_xor(ssa, 4); ssb += __shfl_xor(ssb, 4);
            ssa += __shfl_xor(ssa, 8); ssb += __shfl_xor(ssb, 8);
            const float inva = 1.0f / fmaxf(sqrtf(ssa), 1e-12f);
            const float invb = 1.0f / fmaxf(sqrtf(ssb), 1e-12f);
            const int orow = m * 16 + (lane >> 4) * 4 + r;   // 0..63
            if (FUSED) {
                #pragma unroll
                for (int n = 0; n < 4; ++n)
                    zbuf[orow * D_DIM + cb + n * 16] = f2bf(v[n] * inva);
                #pragma unroll
                for (int n = 4; n < 8; ++n)
                    zbuf[orow * D_DIM + cb + n * 16] = f2bf(v[n] * invb);
            } else {
                #pragma unroll
                for (int n = 0; n < 4; ++n)
                    Zs[(row0 + orow) * D_DIM + cb + n * 16] = f2bf(v[n] * inva);
                #pragma unroll
                for (int n = 4; n < 8; ++n)
                    Zs[(row0 + orow) * D_DIM + cb + n * 16] = f2bf(v[n] * invb);
            }
        }
    }

    if (!FUSED) return;
    __syncthreads();   // zbuf complete

    // ---- routing (round-5 verified code): 2 sites/block, 128 threads each.
    float* const scratch = (float*)smem;          // aliases lAf32 (free now)
    const int tt = t & 127;
    const int ssid = t >> 7;
    const size_t site = (size_t)blockIdx.x * 2 + ssid;
    float* const u_ = scratch + ssid * 512;                 // [0, 4096) bytes
    float* const p_ = (float*)(smem + 4096) + ssid * 256;   // [4096, 6144)
    const short* const zr = zbuf + ssid * 32 * D_DIM;

    const int e = tt * 4;
    const int go = tt >> 4;                  // capsule group of owned elems
    const short4v sv = *reinterpret_cast<const short4v*>(S + site * D_DIM + e);
    const float s0 = bf2f(sv[0]), s1 = bf2f(sv[1]);
    const float s2 = bf2f(sv[2]), s3 = bf2f(sv[3]);

    float v0, v1, v2, v3;
    {   // iteration 0: p uniform 1/8
        float a0 = 0, a1 = 0, a2 = 0, a3 = 0;
        for (int m = 0; m < 32; ++m) {
            const short4v z = *reinterpret_cast<const short4v*>(zr + m * D_DIM + e);
            a0 += bf2f(z[0]); a1 += bf2f(z[1]); a2 += bf2f(z[2]); a3 += bf2f(z[3]);
        }
        v0 = fmaf(a0, 0.125f, s0); v1 = fmaf(a1, 0.125f, s1);
        v2 = fmaf(a2, 0.125f, s2); v3 = fmaf(a3, 0.125f, s3);
    }

    const int dm = tt >> 2;                  // neighbor for this thread's dots
    const int ka = (tt & 3) * 2;             // capsule pair

    for (int it = 1; it < miter; ++it) {
        // normalize u per 64-group (16-thread shfl groups, wave-aligned)
        float ssum = v0 * v0 + v1 * v1 + v2 * v2 + v3 * v3;
        ssum += __shfl_xor(ssum, 1);
        ssum += __shfl_xor(ssum, 2);
        ssum += __shfl_xor(ssum, 4);
        ssum += __shfl_xor(ssum, 8);
        const float inv = 1.0f / fmaxf(sqrtf(ssum), 1e-12f);
        v0 *= inv; v1 *= inv; v2 *= inv; v3 *= inv;
        *reinterpret_cast<float4*>(u_ + e) = make_float4(v0, v1, v2, v3);
        __syncthreads();

        // dots: p[dm][ka], p[dm][ka+1]; staggered octet reads
        const short* const za = zr + dm * D_DIM + ka * 64;
        const float* const ua = u_ + ka * 64;
        float da = 0, db = 0;
        #pragma unroll
        for (int j = 0; j < 8; ++j) {
            const int jj = ((j + (tt & 7)) & 7) * 8;
            const short8 zva = *reinterpret_cast<const short8*>(za + jj);
            const short8 zvb = *reinterpret_cast<const short8*>(za + 64 + jj);
            const f32x4 uA0 = *reinterpret_cast<const f32x4*>(ua + jj);
            const f32x4 uA1 = *reinterpret_cast<const f32x4*>(ua + jj + 4);
            const f32x4 uB0 = *reinterpret_cast<const f32x4*>(ua + 64 + jj);
            const f32x4 uB1 = *reinterpret_cast<const f32x4*>(ua + 64 + jj + 4);
            #pragma unroll
            for (int qq = 0; qq < 4; ++qq) {
                da = fmaf(bf2f(zva[qq]), uA0[qq], da);
                da = fmaf(bf2f(zva[qq + 4]), uA1[qq], da);
                db = fmaf(bf2f(zvb[qq]), uB0[qq], db);
                db = fmaf(bf2f(zvb[qq + 4]), uB1[qq], db);
            }
        }
        // softmax over 8 k (4 threads x 2 vals)
        float mx = fmaxf(da, db);
        mx = fmaxf(mx, __shfl_xor(mx, 1));
        mx = fmaxf(mx, __shfl_xor(mx, 2));
        const float ea = __expf(da - mx), eb = __expf(db - mx);
        float sm_ = ea + eb;
        sm_ += __shfl_xor(sm_, 1);
        sm_ += __shfl_xor(sm_, 2);
        const float rs = 1.0f / sm_;
        *reinterpret_cast<float2*>(p_ + dm * 8 + ka) = make_float2(ea * rs, eb * rs);
        __syncthreads();

        // u = s + sum_m z[m]*p[m, go]
        float a0 = 0, a1 = 0, a2 = 0, a3 = 0;
        for (int m = 0; m < 32; ++m) {
            const short4v z = *reinterpret_cast<const short4v*>(zr + m * D_DIM + e);
            const float pm = p_[m * 8 + go];
            a0 = fmaf(bf2f(z[0]), pm, a0); a1 = fmaf(bf2f(z[1]), pm, a1);
            a2 = fmaf(bf2f(z[2]), pm, a2); a3 = fmaf(bf2f(z[3]), pm, a3);
        }
        v0 = s0 + a0; v1 = s1 + a1; v2 = s2 + a2; v3 = s3 + a3;
        // next p_ write is after next norm's barrier -> safe
    }

    *reinterpret_cast<float4*>(out + site * D_DIM + e) =
        make_float4(fmaxf(v0, 0.0f), fmaxf(v1, 0.0f),
                    fmaxf(v2, 0.0f), fmaxf(v3, 0.0f));
}

extern "C" void kernel_launch(void* const* d_in, const int* in_sizes, int n_in,
                              void* d_out, int out_size, void* d_ws, size_t ws_size,
                              hipStream_t stream) {
    const float* self_v  = (const float*)d_in[0];   // [6400,512]
    const float* neigh_v = (const float*)d_in[1];   // [204800,512]
    const float* W1      = (const float*)d_in[2];   // [512,512]
    const float* b1      = (const float*)d_in[3];   // [512]
    const int*   miter   = (const int*)d_in[4];
    float* out = (float*)d_out;

    const int sites = in_sizes[0] / D_DIM;          // 6400
    const int nrows = in_sizes[1] / D_DIM;          // 204800

    short* s  = (short*)d_ws;                       // [sites,512] bf16
    short* Wb = s + (size_t)sites * D_DIM;          // [512,512] bf16

    wconv<<<dim3(D_DIM * D_DIM / (256 * 8)), dim3(256), 0, stream>>>(W1, Wb);
    gemm_route<false><<<dim3(sites / BM), dim3(256), 0, stream>>>(
        self_v, Wb, b1, s, nullptr, nullptr, nullptr);
    gemm_route<true><<<dim3(nrows / BM), dim3(256), 0, stream>>>(
        neigh_v, Wb, b1, nullptr, s, miter, out);
}